// Round 9
// baseline (127.035 us; speedup 1.0000x reference)
//
#include <hip/hip_runtime.h>

typedef unsigned long long u64;
typedef unsigned int u32;

#define D_FEAT 32
#define NPB 128             // nodes per bucket
#define BSHIFT 7            // log2(NPB)
#define NB_MAX 1024         // max bucket count (guard)
#define NSLICE 8            // sub-regions per bucket (XCD proxy via blockIdx&7)
#define SUBCAP 512          // slots per sub-region (mean 256, +17 sigma)
#define BUCK_OUT (NSLICE * SUBCAP)   // 4096 = per-bucket region in bufB / LDS stage
#define CURPAD 16           // pad cursors to 64 B
#define OVF_MAX 65536
#define SBLK 2048           // scatter blocks

// ---------- K1: single-pass scatter into (bucket, slice) sub-regions ----------
__global__ void __launch_bounds__(256)
scatter1(const int* __restrict__ ei, const float* __restrict__ attr,
         int* __restrict__ cur, int* __restrict__ ovfcnt,
         u64* __restrict__ regions, u64* __restrict__ ovf, int E) {
    const int j = blockIdx.x & (NSLICE - 1);       // slice = XCD proxy
    const int tid = blockIdx.x * blockDim.x + threadIdx.x;
    const int nthr = gridDim.x * blockDim.x;

    const int E4 = E >> 2;
    const int4* src4 = (const int4*)ei;
    const int4* dst4 = (const int4*)(ei + E);
    const float4* att4 = (const float4*)attr;

    for (int i = tid; i < E4; i += nthr) {
        const int4 s4 = src4[i];
        const int4 d4 = dst4[i];
        const float4 a4 = att4[i];
        #pragma unroll
        for (int q = 0; q < 4; ++q) {
            const int s = (&s4.x)[q];
            const u32 d = (u32)(&d4.x)[q];
            const u32 a = __float_as_uint((&a4.x)[q]);
            const int b = s >> BSHIFT;
            const int slot = atomicAdd(&cur[(b * NSLICE + j) * CURPAD], 1);
            const u64 p = ((u64)a << 32) | (d | ((u32)(s & (NPB - 1)) << 20));
            if (slot < SUBCAP) {
                regions[((size_t)(b * NSLICE + j) << 9) + slot] = p;  // <<9 == *SUBCAP
            } else {
                int o = atomicAdd(ovfcnt, 1);
                if (o < OVF_MAX) { ovf[2 * o] = p; ovf[2 * o + 1] = (u64)(u32)s; }
            }
        }
    }
    // scalar tail
    for (int e = (E4 << 2) + tid; e < E; e += nthr) {
        const int s = ei[e];
        const u32 d = (u32)ei[E + e];
        const u32 a = __float_as_uint(attr[e]);
        const int b = s >> BSHIFT;
        const int slot = atomicAdd(&cur[(b * NSLICE + j) * CURPAD], 1);
        const u64 p = ((u64)a << 32) | (d | ((u32)(s & (NPB - 1)) << 20));
        if (slot < SUBCAP) {
            regions[((size_t)(b * NSLICE + j) << 9) + slot] = p;
        } else {
            int o = atomicAdd(ovfcnt, 1);
            if (o < OVF_MAX) { ovf[2 * o] = p; ovf[2 * o + 1] = (u64)(u32)s; }
        }
    }
}

// ---------- K2: per-bucket compaction + node-order sort, fixed output base ----------
__global__ void __launch_bounds__(512)
bucket_sort(const u64* __restrict__ regions, const int* __restrict__ cur,
            u64* __restrict__ bufB, int* __restrict__ seg_start,
            int* __restrict__ seg_end, int N, int NB) {
    __shared__ u64 stage[BUCK_OUT];   // 32 KB
    __shared__ int jofs[NSLICE + 1];
    __shared__ int hist[NPB];
    __shared__ int curL[NPB];
    const int k = blockIdx.x, t = threadIdx.x;

    if (t == 0) {
        int run = 0;
        #pragma unroll
        for (int j = 0; j < NSLICE; ++j) {
            jofs[j] = run;
            int c = cur[(k * NSLICE + j) * CURPAD];
            run += (c < SUBCAP) ? c : SUBCAP;
        }
        jofs[NSLICE] = run;
    }
    if (t < NPB) hist[t] = 0;
    __syncthreads();

    // stage all slices contiguously into LDS
    #pragma unroll
    for (int j = 0; j < NSLICE; ++j) {
        const int ofs = jofs[j];
        const int cnt = jofs[j + 1] - ofs;
        const u64* srcr = regions + ((size_t)(k * NSLICE + j) << 9);
        for (int i = t; i < cnt; i += 512) stage[ofs + i] = srcr[i];
    }
    __syncthreads();

    const int total = jofs[NSLICE];
    // histogram by local node
    for (int i = t; i < total; i += 512)
        atomicAdd(&hist[(int)(((u32)stage[i] >> 20) & (NPB - 1))], 1);
    __syncthreads();

    // inclusive scan of 128 counters
    int orig = (t < NPB) ? hist[t] : 0;
    for (int d = 1; d < NPB; d <<= 1) {
        int tmp = (t >= d && t < NPB) ? hist[t - d] : 0;
        __syncthreads();
        if (t < NPB) hist[t] += tmp;
        __syncthreads();
    }
    const int base = k * BUCK_OUT;
    if (t < NPB) {
        const int excl = hist[t] - orig;
        curL[t] = excl;
        const int node = (k << BSHIFT) + t;
        if (node < N) {
            seg_start[node] = base + excl;
            seg_end[node] = base + hist[t];
        }
    }
    __syncthreads();

    // scatter into node order at fixed base
    for (int i = t; i < total; i += 512) {
        const u64 p = stage[i];
        const int local = (int)(((u32)p >> 20) & (NPB - 1));
        const int pos = atomicAdd(&curL[local], 1);
        bufB[base + pos] = p;
    }
}

// ---------- K3: node-parallel gather, 8 lanes/node, float4, 4-edge unroll ----------
__global__ void __launch_bounds__(256)
csr_gather(const u64* __restrict__ csr, const int* __restrict__ seg_start,
           const int* __restrict__ seg_end, const float* __restrict__ x,
           float* __restrict__ out, int N) {
    const int gid = (blockIdx.x * 256 + threadIdx.x) >> 3;  // node
    const int l4 = (threadIdx.x & 7) << 2;                  // feature*4
    if (gid >= N) return;
    const int s = seg_start[gid], e = seg_end[gid];

    float ax = 0.f, ay = 0.f, az = 0.f, aw = 0.f;
    int k = s;
    for (; k + 4 <= e; k += 4) {
        const u64 p0 = csr[k], p1 = csr[k + 1], p2 = csr[k + 2], p3 = csr[k + 3];
        const float4 v0 = *(const float4*)&x[(((size_t)((u32)p0 & 0xFFFFFu)) << 5) + l4];
        const float4 v1 = *(const float4*)&x[(((size_t)((u32)p1 & 0xFFFFFu)) << 5) + l4];
        const float4 v2 = *(const float4*)&x[(((size_t)((u32)p2 & 0xFFFFFu)) << 5) + l4];
        const float4 v3 = *(const float4*)&x[(((size_t)((u32)p3 & 0xFFFFFu)) << 5) + l4];
        const float a0 = __uint_as_float((u32)(p0 >> 32));
        const float a1 = __uint_as_float((u32)(p1 >> 32));
        const float a2 = __uint_as_float((u32)(p2 >> 32));
        const float a3 = __uint_as_float((u32)(p3 >> 32));
        ax = fmaf(a0, v0.x, ax); ay = fmaf(a0, v0.y, ay); az = fmaf(a0, v0.z, az); aw = fmaf(a0, v0.w, aw);
        ax = fmaf(a1, v1.x, ax); ay = fmaf(a1, v1.y, ay); az = fmaf(a1, v1.z, az); aw = fmaf(a1, v1.w, aw);
        ax = fmaf(a2, v2.x, ax); ay = fmaf(a2, v2.y, ay); az = fmaf(a2, v2.z, az); aw = fmaf(a2, v2.w, aw);
        ax = fmaf(a3, v3.x, ax); ay = fmaf(a3, v3.y, ay); az = fmaf(a3, v3.z, az); aw = fmaf(a3, v3.w, aw);
    }
    for (; k < e; ++k) {
        const u64 p = csr[k];
        const float4 v = *(const float4*)&x[(((size_t)((u32)p & 0xFFFFFu)) << 5) + l4];
        const float a = __uint_as_float((u32)(p >> 32));
        ax = fmaf(a, v.x, ax); ay = fmaf(a, v.y, ay); az = fmaf(a, v.z, az); aw = fmaf(a, v.w, aw);
    }
    float4 r; r.x = ax; r.y = ay; r.z = az; r.w = aw;
    *(float4*)&out[((size_t)gid << 5) + l4] = r;
}

// ---------- K4: drain overflow edges (normally zero) via global atomics ----------
__global__ void __launch_bounds__(256)
drain_ovf(const u64* __restrict__ ovf, const int* __restrict__ ovfcnt,
          const float* __restrict__ x, float* __restrict__ out) {
    int n = *ovfcnt;
    if (n > OVF_MAX) n = OVF_MAX;
    const int l4 = (threadIdx.x & 7) << 2;
    const int nthr = (gridDim.x * blockDim.x) >> 3;
    for (int i = (int)((blockIdx.x * blockDim.x + threadIdx.x) >> 3); i < n; i += nthr) {
        const u64 p = ovf[2 * i];
        const int src = (int)(u32)ovf[2 * i + 1];
        const float a = __uint_as_float((u32)(p >> 32));
        const float4 v = *(const float4*)&x[(((size_t)((u32)p & 0xFFFFFu)) << 5) + l4];
        float* ob = &out[((size_t)src << 5) + l4];
        atomicAdd(ob + 0, a * v.x);
        atomicAdd(ob + 1, a * v.y);
        atomicAdd(ob + 2, a * v.z);
        atomicAdd(ob + 3, a * v.w);
    }
}

// ---------- fallback (generality): direct atomic scatter ----------
__global__ void fallback_scatter(const int* __restrict__ ei, const float* __restrict__ attr,
                                 const float* __restrict__ x, float* __restrict__ out, int E) {
    const long long total = (long long)E * D_FEAT;
    const long long stride = (long long)gridDim.x * blockDim.x;
    for (long long i = (long long)blockIdx.x * blockDim.x + threadIdx.x; i < total; i += stride) {
        const int e = (int)(i >> 5);
        const int d = (int)(i & 31);
        atomicAdd(&out[((long long)ei[e] << 5) + d],
                  attr[e] * x[((long long)ei[E + e] << 5) + d]);
    }
}

extern "C" void kernel_launch(void* const* d_in, const int* in_sizes, int n_in,
                              void* d_out, int out_size, void* d_ws, size_t ws_size,
                              hipStream_t stream) {
    const int* edge_index = (const int*)d_in[0];    // [2, E] int32
    const float* edge_attr = (const float*)d_in[1]; // [E] f32
    const float* x = (const float*)d_in[2];         // [N, 32] f32
    float* out = (float*)d_out;                     // [N, 32] f32

    const int E = in_sizes[1];
    const int N = in_sizes[2] / D_FEAT;
    const int NB = (N + NPB - 1) >> BSHIFT;

    // Workspace layout (256-B aligned sections)
    char* ws = (char*)d_ws;
    int* cur = (int*)ws;                                               // NB*NSLICE*CURPAD
    size_t cur_bytes = (size_t)NB * NSLICE * CURPAD * 4;
    size_t o1 = (cur_bytes + 255) & ~(size_t)255;
    int* ovfcnt = (int*)(ws + o1);                                     // 1
    size_t o2 = (o1 + 256 + 255) & ~(size_t)255;
    int* seg_start = (int*)(ws + o2);                                  // N
    size_t o3 = (o2 + ((size_t)N * 4) + 255) & ~(size_t)255;
    int* seg_end = (int*)(ws + o3);                                    // N
    size_t o4 = (o3 + ((size_t)N * 4) + 255) & ~(size_t)255;
    u64* ovf = (u64*)(ws + o4);                                        // 2*OVF_MAX
    size_t o5 = (o4 + ((size_t)OVF_MAX * 16) + 255) & ~(size_t)255;
    u64* regions = (u64*)(ws + o5);                                    // NB*BUCK_OUT
    size_t o6 = (o5 + ((size_t)NB * BUCK_OUT * 8) + 255) & ~(size_t)255;
    u64* bufB = (u64*)(ws + o6);                                       // NB*BUCK_OUT
    size_t need = o6 + (size_t)NB * BUCK_OUT * 8;

    if (NB > NB_MAX || N > (1 << 20) || need > ws_size) {
        hipMemsetAsync(d_out, 0, (size_t)out_size * sizeof(float), stream);
        long long total = (long long)E * D_FEAT;
        int grid = (int)((total + 255) / 256);
        if (grid > 65536) grid = 65536;
        fallback_scatter<<<grid, 256, 0, stream>>>(edge_index, edge_attr, x, out, E);
        return;
    }

    // zero cursors + overflow counter (contiguous prefix of ws)
    hipMemsetAsync(ws, 0, o1 + 256, stream);

    scatter1<<<SBLK, 256, 0, stream>>>(edge_index, edge_attr, cur, ovfcnt, regions, ovf, E);
    bucket_sort<<<NB, 512, 0, stream>>>(regions, cur, bufB, seg_start, seg_end, N, NB);

    const long long gthreads = (long long)N * 8;
    csr_gather<<<(int)((gthreads + 255) / 256), 256, 0, stream>>>(bufB, seg_start, seg_end, x, out, N);
    drain_ovf<<<16, 256, 0, stream>>>(ovf, ovfcnt, x, out);
}